// Round 11
// baseline (698.507 us; speedup 1.0000x reference)
//
#include <hip/hip_runtime.h>
#include <math.h>

#define N_NODES 50000
#define N_EDGES 800000
#define EPSV 1e-8f
#define ALPHA 0.3f

typedef __attribute__((ext_vector_type(8))) unsigned short ushort8;
typedef __attribute__((ext_vector_type(4))) float floatx4;
typedef __attribute__((ext_vector_type(2))) long longx2;
typedef _Float16 half8 __attribute__((ext_vector_type(8)));
typedef _Float16 half2v __attribute__((ext_vector_type(2)));

__device__ inline unsigned short f2h(float f) {
    union { _Float16 h; unsigned short u; } c; c.h = (_Float16)f; return c.u;
}
__device__ inline float h2f(unsigned short u) {
    union { unsigned short u; _Float16 h; } c; c.u = u; return (float)c.h;
}
// fp32 -> OCP e4m3fn, round-nearest-even, saturating
__device__ inline unsigned char f2e4m3(float f) {
    unsigned u = __float_as_uint(f);
    unsigned s = (u >> 24) & 0x80u;
    float af = fabsf(f);
    if (af >= 464.f) return (unsigned char)(s | 0x7Eu);
    if (af < 0.015625f) {
        int m = (int)rintf(af * 512.f);
        return (unsigned char)(s | (unsigned)m);
    }
    unsigned au = __float_as_uint(af);
    unsigned mant = au & 0x7FFFFFu;
    unsigned lsb = (mant >> 20) & 1u;
    mant += 0x7FFFFu + lsb;
    unsigned exp32 = (au >> 23) + (mant >> 23);
    mant &= 0x7FFFFFu;
    unsigned e8 = exp32 - 127u + 7u;
    return (unsigned char)(s | (e8 << 3) | (mant >> 20));
}

// ---------------------------------------------------------------------------
// Graph preprocessing
// ---------------------------------------------------------------------------

__global__ __launch_bounds__(256) void k_count(const int* __restrict__ ei,
                                               int* __restrict__ cnt) {
    int e = blockIdx.x * 256 + threadIdx.x;
    if (e < N_EDGES) atomicAdd(&cnt[__builtin_nontemporal_load(ei + N_EDGES + e)], 1);
}

__global__ __launch_bounds__(256) void k_invdis(const int* __restrict__ cnt,
                                                float* __restrict__ dis,
                                                float* __restrict__ inv) {
    int i = blockIdx.x * 256 + threadIdx.x;
    if (i < N_NODES) {
        float d = (float)cnt[i] + 1.0f;
        dis[i] = 1.0f / sqrtf(d);
        inv[i] = 1.0f / d;
    }
}

__global__ __launch_bounds__(256) void k_scan_partial(const int* __restrict__ cnt,
                                                      int* __restrict__ partial) {
    int b = blockIdx.x, t = threadIdx.x;
    int base = b * 1024 + t * 4;
    int s = 0;
#pragma unroll
    for (int j = 0; j < 4; ++j) {
        int idx = base + j;
        if (idx < N_NODES) s += cnt[idx];
    }
#pragma unroll
    for (int m = 1; m < 64; m <<= 1) s += __shfl_xor(s, m, 64);
    __shared__ int sh[4];
    if ((t & 63) == 0) sh[t >> 6] = s;
    __syncthreads();
    if (t == 0) partial[b] = sh[0] + sh[1] + sh[2] + sh[3];
}

__global__ void k_scan_mid(int* __restrict__ partial, int* __restrict__ rowptr) {
    int l = threadIdx.x;
    const int NP = (N_NODES + 1023) / 1024;
    int v = (l < NP) ? partial[l] : 0;
    int vin = v;
#pragma unroll
    for (int off = 1; off < 64; off <<= 1) {
        int u = __shfl_up(v, off, 64);
        if (l >= off) v += u;
    }
    if (l < NP) partial[l] = v - vin;
    if (l == NP - 1) rowptr[N_NODES] = v;
}

__global__ __launch_bounds__(256) void k_scan_final(const int* __restrict__ cnt,
                                                    const int* __restrict__ partial,
                                                    int* __restrict__ rowptr) {
    int b = blockIdx.x, t = threadIdx.x;
    int base = b * 1024 + t * 4;
    int c[4];
    int s = 0;
#pragma unroll
    for (int j = 0; j < 4; ++j) {
        int idx = base + j;
        c[j] = (idx < N_NODES) ? cnt[idx] : 0;
        s += c[j];
    }
    __shared__ int sh[256];
    sh[t] = s;
    __syncthreads();
    for (int off = 1; off < 256; off <<= 1) {
        int v = 0;
        if (t >= off) v = sh[t - off];
        __syncthreads();
        sh[t] += v;
        __syncthreads();
    }
    int texcl = sh[t] - s;
    int pre = partial[b] + texcl;
#pragma unroll
    for (int j = 0; j < 4; ++j) {
        int idx = base + j;
        if (idx < N_NODES) rowptr[idx] = pre;
        pre += c[j];
    }
}

// builds CSR col list AND the aligned dst list (edge list sorted by dst)
__global__ __launch_bounds__(256) void k_fill(const int* __restrict__ ei,
                                              const int* __restrict__ rowptr,
                                              int* __restrict__ cursor,
                                              int* __restrict__ col,
                                              int* __restrict__ dstl) {
    int e = blockIdx.x * 256 + threadIdx.x;
    if (e < N_EDGES) {
        int d = __builtin_nontemporal_load(ei + N_EDGES + e);
        int pos = rowptr[d] + atomicAdd(&cursor[d], 1);
        col[pos] = __builtin_nontemporal_load(ei + e);
        dstl[pos] = d;
    }
}

__global__ __launch_bounds__(256) void k_t(const int* __restrict__ ei,
                                           const int* __restrict__ qp,
                                           const float* __restrict__ dis,
                                           const float* __restrict__ inv,
                                           float* __restrict__ t) {
    int e = blockIdx.x * 256 + threadIdx.x;
    int q = *qp;
    if (e == 0) atomicAdd(&t[q], inv[q]);
    if (e < N_EDGES && __builtin_nontemporal_load(ei + e) == q) {
        int d = ei[N_EDGES + e];
        atomicAdd(&t[d], dis[q] * dis[d]);
    }
}

// flag = 1 iff bq0 and bq1 are all-zero (enables exact rank-1 hq tower)
__global__ void k_flag(const float* __restrict__ bq0, const float* __restrict__ bq1,
                       int* __restrict__ flag) {
    int j = threadIdx.x;  // 256
    float v = (j < 128) ? bq0[j] : bq1[j - 128];
    unsigned long long b = __ballot(v != 0.f);
    __shared__ int bad[4];
    if ((j & 63) == 0) bad[j >> 6] = (b != 0ull);
    __syncthreads();
    if (j == 0) flag[0] = !(bad[0] | bad[1] | bad[2] | bad[3]);
}

// r0 = relu(wq0)   [rank-1 path]
__global__ void k_r0(const int* __restrict__ gflag, const float* __restrict__ wq0,
                     float* __restrict__ r0) {
    if (*gflag != 1) return;
    int j = threadIdx.x;  // 128
    r0[j] = fmaxf(wq0[j], 0.f);
}

// vout[c] = (relu?)( sum_k W[c][k]*vin[k] )   [rank-1 path, gated]
template <int RELU>
__global__ void k_matvec(const int* __restrict__ gflag, const float* __restrict__ W,
                         const float* __restrict__ vin, float* __restrict__ vout) {
    if (*gflag != 1) return;
    int c = blockIdx.x, l = threadIdx.x;  // 128 blocks x 64
    float2 w = *(const float2*)(W + c * 128 + 2 * l);
    float2 v = *(const float2*)(vin + 2 * l);
    float s = w.x * v.x + w.y * v.y;
#pragma unroll
    for (int m = 1; m < 64; m <<= 1) s += __shfl_xor(s, m, 64);
    if (l == 0) vout[c] = RELU ? fmaxf(s, 0.f) : s;
}

// vout = Ahat * vin  (scalar SpMV)   [rank-1 path, gated]
__global__ __launch_bounds__(256) void k_spmv(const int* __restrict__ gflag,
                                              const int* __restrict__ rowptr,
                                              const int* __restrict__ col,
                                              const float* __restrict__ dis,
                                              const float* __restrict__ inv,
                                              const float* __restrict__ vin,
                                              float* __restrict__ vout) {
    if (*gflag != 1) return;
    int i = blockIdx.x * 256 + threadIdx.x;
    if (i >= N_NODES) return;
    int r0 = rowptr[i], r1 = rowptr[i + 1];
    float s = 0.f;
    for (int e = r0; e < r1; ++e) {
        int c = col[e];
        s += dis[c] * vin[c];
    }
    vout[i] = fmaf(inv[i], vin[i], dis[i] * s);
}

// fp32 -> fp16 cast
__global__ __launch_bounds__(256) void k_cast(const float* __restrict__ in,
                                              unsigned short* __restrict__ out, int n8) {
    int id = blockIdx.x * 256 + threadIdx.x;
    if (id >= n8) return;
    const float4 a = *(const float4*)(in + id * 8);
    const float4 b = *(const float4*)(in + id * 8 + 4);
    ushort8 o;
    o[0] = f2h(a.x); o[1] = f2h(a.y); o[2] = f2h(a.z); o[3] = f2h(a.w);
    o[4] = f2h(b.x); o[5] = f2h(b.y); o[6] = f2h(b.z); o[7] = f2h(b.w);
    *(ushort8*)(out + id * 8) = o;
}

struct WPack { const float* w[11]; };
__global__ __launch_bounds__(256) void k_castw(WPack wp, unsigned short* __restrict__ out) {
    int m = blockIdx.y;
    int id = blockIdx.x * 256 + threadIdx.x;
    const float* src = wp.w[m] + id * 8;
    float4 a = *(const float4*)src;
    float4 b = *(const float4*)(src + 4);
    ushort8 o;
    o[0] = f2h(a.x); o[1] = f2h(a.y); o[2] = f2h(a.z); o[3] = f2h(a.w);
    o[4] = f2h(b.x); o[5] = f2h(b.y); o[6] = f2h(b.z); o[7] = f2h(b.w);
    *(ushort8*)(out + m * 16384 + id * 8) = o;
}

// xf -> fp8 table, permuted: byte p = kb*32 + m*8 + j  holds value k = m*32 + kb*8 + j
__global__ __launch_bounds__(256) void k_cast8(const float* __restrict__ xf,
                                               unsigned char* __restrict__ xq8) {
    int id = blockIdx.x * 256 + threadIdx.x;
    int node = id >> 3, c = id & 7;
    if (node >= N_NODES) return;
    int kb = c >> 1, mb = (c & 1) * 2;
    const float* base = xf + (size_t)node * 128;
    const float* p0 = base + mb * 32 + kb * 8;
    const float* p1 = base + (mb + 1) * 32 + kb * 8;
    union { unsigned char b[16]; uint4 u; } o;
#pragma unroll
    for (int j = 0; j < 8; ++j) o.b[j] = f2e4m3(p0[j]);
#pragma unroll
    for (int j = 0; j < 8; ++j) o.b[8 + j] = f2e4m3(p1[j]);
    *(uint4*)(xq8 + (size_t)node * 128 + c * 16) = o.u;
}

// ---------------------------------------------------------------------------
// MFMA fp16 GEMM, A/W staged via global_load_lds (pre-swizzled source).
// ---------------------------------------------------------------------------

template <int RELU, int NADD, int HASB2, int WOUT, int RK1>
__global__ __launch_bounds__(256) void k_gemm(
    const unsigned short* __restrict__ A, int As,
    const unsigned short* __restrict__ Wb,
    const float* __restrict__ bias, const float* __restrict__ bias2,
    const unsigned short* __restrict__ add1, int a1s,
    const unsigned short* __restrict__ add2, int a2s,
    const float* __restrict__ u, const float* __restrict__ vq,
    const int* __restrict__ gflag, int want,
    unsigned short* __restrict__ outh, int ohs,
    float* __restrict__ outf, int ofs, int nrows) {
    if (gflag && *gflag != want) return;
    __shared__ unsigned short Al[128 * 128];
    __shared__ unsigned short Wl[128 * 128];
    const int tid = threadIdx.x;
    const int row0 = blockIdx.x * 128;
    const int wv = tid >> 6;
    const int t4 = tid >> 4, c16 = tid & 15;

#pragma unroll
    for (int it = 0; it < 8; ++it) {
        int r = it * 16 + t4;
        int gr = row0 + r; if (gr > nrows - 1) gr = nrows - 1;
        int sw = (c16 * 16) ^ ((r & 7) << 4);
        const char* srcA = (const char*)(A + (size_t)gr * As) + sw;
        __builtin_amdgcn_global_load_lds(
            (const __attribute__((address_space(1))) void*)srcA,
            (__attribute__((address_space(3))) void*)(Al + it * 2048 + wv * 512),
            16, 0, 0);
        const char* srcW = (const char*)(Wb + r * 128) + sw;
        __builtin_amdgcn_global_load_lds(
            (const __attribute__((address_space(1))) void*)srcW,
            (__attribute__((address_space(3))) void*)(Wl + it * 2048 + wv * 512),
            16, 0, 0);
    }
    __syncthreads();

    const int l = tid & 63;
    const int lr = l & 15, lg = l >> 4;
    const int sx = (lr & 7) << 4;

    floatx4 acc[8][2];
#pragma unroll
    for (int i = 0; i < 8; ++i)
#pragma unroll
        for (int j = 0; j < 2; ++j) acc[i][j] = (floatx4){0.f, 0.f, 0.f, 0.f};

#pragma unroll
    for (int ks = 0; ks < 4; ++ks) {
        int ko = (ks * 64 + lg * 16) ^ sx;
        half8 bfr[2];
#pragma unroll
        for (int ct = 0; ct < 2; ++ct) {
            int c = wv * 32 + ct * 16 + lr;
            bfr[ct] = *(const half8*)((char*)Wl + c * 256 + ko);
        }
#pragma unroll
        for (int rt = 0; rt < 8; ++rt) {
            int r = rt * 16 + lr;
            half8 af = *(const half8*)((char*)Al + r * 256 + ko);
            acc[rt][0] = __builtin_amdgcn_mfma_f32_16x16x32_f16(af, bfr[0], acc[rt][0], 0, 0, 0);
            acc[rt][1] = __builtin_amdgcn_mfma_f32_16x16x32_f16(af, bfr[1], acc[rt][1], 0, 0, 0);
        }
    }

    // C/D layout: col=lane&15, row=(lane>>4)*4+reg
#pragma unroll
    for (int ct = 0; ct < 2; ++ct) {
        int colc = wv * 32 + ct * 16 + lr;
        float bv = bias[colc];
        if (HASB2) bv += bias2[colc];
        float vqc = RK1 ? vq[colc] : 0.f;
#pragma unroll
        for (int rt = 0; rt < 8; ++rt) {
            int rbase = row0 + rt * 16 + lg * 4;
#pragma unroll
            for (int reg = 0; reg < 4; ++reg) {
                int r = rbase + reg;
                if (r >= nrows) continue;
                float v = acc[rt][ct][reg] + bv;
                if (RK1) v = fmaf(u[r], vqc, v);
                if (NADD >= 1) v += h2f(add1[(size_t)r * a1s + colc]);
                if (NADD >= 2) v += h2f(add2[(size_t)r * a2s + colc]);
                if (RELU) v = fmaxf(v, 0.f);
                if (WOUT) outf[(size_t)r * ofs + colc] = v;
                else outh[(size_t)r * ohs + colc] = f2h(v);
            }
        }
    }
}

// ---------------------------------------------------------------------------
// SpMM, fp16 packed-FMA, NUM streams, edge loop unrolled x2 (8 edges in
// flight per wave) with dual accumulator sets.
// ---------------------------------------------------------------------------

template <int NUM>
__global__ __launch_bounds__(256) void k_agg(
    const int* __restrict__ gflag, int want,
    const int* __restrict__ rowptr, const int* __restrict__ col,
    const float* __restrict__ dis, const float* __restrict__ inv,
    const unsigned short* __restrict__ in0, int s0,
    const unsigned short* __restrict__ in1, int s1,
    const unsigned short* __restrict__ in2, int s2,
    unsigned short* __restrict__ out, int o0, int o1, int o2) {
    if (gflag && *gflag != want) return;
    int i = blockIdx.x * 4 + (threadIdx.x >> 6);
    int l = threadIdx.x & 63;
    int g = l >> 4, li = l & 15;
    int r0 = rowptr[i], r1 = rowptr[i + 1];

    half2v accA[NUM][4], accB[NUM][4];
#pragma unroll
    for (int b = 0; b < NUM; ++b)
#pragma unroll
        for (int j = 0; j < 4; ++j) {
            accA[b][j] = (half2v){(_Float16)0, (_Float16)0};
            accB[b][j] = (half2v){(_Float16)0, (_Float16)0};
        }

    union U8 { ushort8 u; half2v h[4]; };
    const unsigned short* ins[3] = {in0, in1, in2};
    const int ss[3] = {s0, s1, s2};

    for (int base = r0; base < r1; base += 8) {
        int eA = base + g, eB = base + 4 + g;
        int sA = i; float wA = 0.f;
        if (eA < r1) { sA = col[eA]; wA = dis[sA]; }
        int sB = i; float wB = 0.f;
        if (eB < r1) { sB = col[eB]; wB = dis[sB]; }
        _Float16 whA = (_Float16)wA, whB = (_Float16)wB;
        half2v w2A = {whA, whA}, w2B = {whB, whB};
        U8 vA[NUM], vB[NUM];
#pragma unroll
        for (int b = 0; b < NUM; ++b) {
            vA[b].u = *(const ushort8*)(ins[b] + (size_t)sA * ss[b] + li * 8);
            vB[b].u = *(const ushort8*)(ins[b] + (size_t)sB * ss[b] + li * 8);
        }
#pragma unroll
        for (int b = 0; b < NUM; ++b)
#pragma unroll
            for (int j = 0; j < 4; ++j) {
                accA[b][j] += vA[b].h[j] * w2A;
                accB[b][j] += vB[b].h[j] * w2B;
            }
    }
    union U2 { half2v h; int i; };
#pragma unroll
    for (int b = 0; b < NUM; ++b)
#pragma unroll
        for (int j = 0; j < 4; ++j) {
            U2 c, o;
            c.h = accA[b][j] + accB[b][j];
            o.i = __shfl_xor(c.i, 16, 64); c.h += o.h;
            o.i = __shfl_xor(c.i, 32, 64); c.h += o.h;
            accA[b][j] = c.h;
        }
    if (g == 0) {
        float di = dis[i], iv = inv[i];
        const int oo[3] = {o0, o1, o2};
#pragma unroll
        for (int b = 0; b < NUM; ++b) {
            U8 sv;
            sv.u = *(const ushort8*)(ins[b] + (size_t)i * ss[b] + li * 8);
            ushort8 o;
#pragma unroll
            for (int j = 0; j < 4; ++j) {
                float a0 = fmaf(di, (float)accA[b][j][0], iv * (float)sv.h[j][0]);
                float a1 = fmaf(di, (float)accA[b][j][1], iv * (float)sv.h[j][1]);
                o[2 * j] = f2h(a0);
                o[2 * j + 1] = f2h(a1);
            }
            *(ushort8*)(out + (size_t)i * 384 + oo[b] + li * 8) = o;
        }
    }
}

// hq0[i][j] = relu(t[i]*wq0[j] + bq0[j])   [full path only]
__global__ __launch_bounds__(256) void k_hq0(const int* __restrict__ gflag,
                                             const float* __restrict__ t,
                                             const float* __restrict__ wq0,
                                             const float* __restrict__ bq0,
                                             unsigned short* __restrict__ B1h) {
    if (*gflag != 0) return;
    int gidx = blockIdx.x * 256 + threadIdx.x;
    int i = gidx >> 7, j = gidx & 127;
    B1h[(size_t)i * 384 + j] = f2h(fmaxf(fmaf(t[i], wq0[j], bq0[j]), 0.f));
}

__global__ void k_addwlq(const int* __restrict__ qp, const float* __restrict__ w_lq,
                         unsigned short* __restrict__ z0h) {
    int j = threadIdx.x;
    int q = *qp;
    z0h[(size_t)q * 128 + j] = f2h(h2f(z0h[(size_t)q * 128 + j]) + w_lq[j]);
}

// ---------------------------------------------------------------------------
// Decode
// ---------------------------------------------------------------------------

__global__ void k_qemb(const int* __restrict__ qp, const float* __restrict__ xf,
                       float* __restrict__ qe) {
    int j = threadIdx.x;  // 128
    int q = *qp;
    float v = xf[(size_t)q * 128 + j];
    qe[j] = v;
    float s = v * v;
#pragma unroll
    for (int m = 1; m < 64; m <<= 1) s += __shfl_xor(s, m, 64);
    __shared__ float sh[2];
    if ((j & 63) == 0) sh[j >> 6] = s;
    __syncthreads();
    if (j == 0) qe[128] = fmaxf(sqrtf(sh[0] + sh[1]), EPSV);
}

__global__ __launch_bounds__(256) void k_node(const float* __restrict__ xf,
                                              const float* __restrict__ qe,
                                              const float* __restrict__ m2w1,
                                              const float* __restrict__ m2b1,
                                              const float* __restrict__ m2w2,
                                              const float* __restrict__ m2b2,
                                              float* __restrict__ out,
                                              float* __restrict__ a,
                                              float* __restrict__ n2) {
    int node = blockIdx.x * 4 + (threadIdx.x >> 6);
    int lane = threadIdx.x & 63;
    const float2 xv = *(const float2*)(xf + (size_t)node * 128 + 2 * lane);
    const float2 qv = *(const float2*)(qe + 2 * lane);
    const float2 wv = *(const float2*)(m2w1 + 2 * lane);
    float dq = xv.x * qv.x + xv.y * qv.y;
    float dx = xv.x * xv.x + xv.y * xv.y;
    float dw = xv.x * wv.x + xv.y * wv.y;
#pragma unroll
    for (int m = 1; m < 64; m <<= 1) {
        dq += __shfl_xor(dq, m, 64);
        dx += __shfl_xor(dx, m, 64);
        dw += __shfl_xor(dw, m, 64);
    }
    if (lane == 0) {
        float qn = qe[128];
        float vn = fmaxf(sqrtf(dx), EPSV);
        float simq = dq / (vn * qn);
        float l1 = dw + m2b1[0];
        float s2 = fmaxf(l1, 0.f) * m2w2[0] + m2b2[0];
        float sim = ((1.f - ALPHA) * simq + ALPHA * s2) * 2.f;
        out[node] = 1.f / (1.f + expf(-sim));
        a[node] = dq;
        n2[node] = dx;
    }
}

// fused pos+neg edge BCE via fp8 MFMA-diag, 2-tile software pipeline.
// Edges consumed in DST-SORTED order (loss is permutation-invariant):
// within a tile, d-values cluster -> d-row gathers are L1/L2 hits.
__global__ __launch_bounds__(256) void k_loss(const int* __restrict__ colP,
                                              const int* __restrict__ dstP,
                                              const int* __restrict__ colN,
                                              const int* __restrict__ dstN,
                                              const unsigned char* __restrict__ xq8,
                                              const float* __restrict__ a,
                                              const float* __restrict__ n2,
                                              const float* __restrict__ qe,
                                              float* __restrict__ lossout) {
    int l = threadIdx.x & 63, wvi = threadIdx.x >> 6;
    int i16 = l & 15;
    int kb = l >> 4;
    int gw = blockIdx.x * 4 + wvi;
    const int NW = gridDim.x * 4;
    const int NT = 2 * N_EDGES / 16;  // tiles of 16 edges, purely pos or neg
    float qn = qe[128];
    float local = 0.f;
    const int rsel = l & 3;
    const int srcl = ((i16 >> 2) << 4) + i16;

    int t = gw;
    for (; t + NW < NT; t += 2 * NW) {
        int baseA = t * 16;
        int negA = baseA >= N_EDGES;
        const int* slA = negA ? colN : colP;
        const int* dlA = negA ? dstN : dstP;
        int eoA = (negA ? baseA - N_EDGES : baseA) + i16;
        int sA = slA[eoA];
        int dA = dlA[eoA];

        int baseB = (t + NW) * 16;
        int negB = baseB >= N_EDGES;
        const int* slB = negB ? colN : colP;
        const int* dlB = negB ? dstN : dstP;
        int eoB = (negB ? baseB - N_EDGES : baseB) + i16;
        int sB = slB[eoB];
        int dB = dlB[eoB];

        const unsigned char* psA = xq8 + (size_t)sA * 128 + kb * 32;
        const unsigned char* pdA = xq8 + (size_t)dA * 128 + kb * 32;
        longx2 a01A = *(const longx2*)psA;
        longx2 a23A = *(const longx2*)(psA + 16);
        longx2 b01A = *(const longx2*)pdA;
        longx2 b23A = *(const longx2*)(pdA + 16);

        const unsigned char* psB = xq8 + (size_t)sB * 128 + kb * 32;
        const unsigned char* pdB = xq8 + (size_t)dB * 128 + kb * 32;
        longx2 a01B = *(const longx2*)psB;
        longx2 a23B = *(const longx2*)(psB + 16);
        longx2 b01B = *(const longx2*)pdB;
        longx2 b23B = *(const longx2*)(pdB + 16);

        float n2sA = 0.f, n2dA = 0.f, asA = 0.f, adA = 0.f;
        float n2sB = 0.f, n2dB = 0.f, asB = 0.f, adB = 0.f;
        if (l < 16) {
            n2sA = n2[sA]; n2dA = n2[dA]; asA = a[sA]; adA = a[dA];
            n2sB = n2[sB]; n2dB = n2[dB]; asB = a[sB]; adB = a[dB];
        }

        {
            floatx4 acc = (floatx4){0.f, 0.f, 0.f, 0.f};
            acc = __builtin_amdgcn_mfma_f32_16x16x32_fp8_fp8(a01A[0], b01A[0], acc, 0, 0, 0);
            acc = __builtin_amdgcn_mfma_f32_16x16x32_fp8_fp8(a01A[1], b01A[1], acc, 0, 0, 0);
            acc = __builtin_amdgcn_mfma_f32_16x16x32_fp8_fp8(a23A[0], b23A[0], acc, 0, 0, 0);
            acc = __builtin_amdgcn_mfma_f32_16x16x32_fp8_fp8(a23A[1], b23A[1], acc, 0, 0, 0);
            float v = acc[0];
            v = (rsel == 1) ? acc[1] : v;
            v = (rsel == 2) ? acc[2] : v;
            v = (rsel == 3) ? acc[3] : v;
            float dsd = __int_as_float(
                __builtin_amdgcn_ds_bpermute(srcl << 2, __float_as_int(v)));
            if (l < 16) {
                float nv = 0.25f * (n2sA + n2dA + 2.f * dsd);
                float vn = fmaxf(sqrtf(fmaxf(nv, 0.f)), EPSV);
                float cs = (0.5f * (asA + adA)) / (vn * qn);
                float sg = negA ? cs : -cs;
                local += log1pf(expf(sg));
            }
        }
        {
            floatx4 acc = (floatx4){0.f, 0.f, 0.f, 0.f};
            acc = __builtin_amdgcn_mfma_f32_16x16x32_fp8_fp8(a01B[0], b01B[0], acc, 0, 0, 0);
            acc = __builtin_amdgcn_mfma_f32_16x16x32_fp8_fp8(a01B[1], b01B[1], acc, 0, 0, 0);
            acc = __builtin_amdgcn_mfma_f32_16x16x32_fp8_fp8(a23B[0], b23B[0], acc, 0, 0, 0);
            acc = __builtin_amdgcn_mfma_f32_16x16x32_fp8_fp8(a23B[1], b23B[1], acc, 0, 0, 0);
            float v = acc[0];
            v = (rsel == 1) ? acc[1] : v;
            v = (rsel == 2) ? acc[2] : v;
            v = (rsel == 3) ? acc[3] : v;
            float dsd = __int_as_float(
                __builtin_amdgcn_ds_bpermute(srcl << 2, __float_as_int(v)));
            if (l < 16) {
                float nv = 0.25f * (n2sB + n2dB + 2.f * dsd);
                float vn = fmaxf(sqrtf(fmaxf(nv, 0.f)), EPSV);
                float cs = (0.5f * (asB + adB)) / (vn * qn);
                float sg = negB ? cs : -cs;
                local += log1pf(expf(sg));
            }
        }
    }
    if (t < NT) {  // remainder tile
        int base = t * 16;
        int neg = base >= N_EDGES;
        const int* sl = neg ? colN : colP;
        const int* dl = neg ? dstN : dstP;
        int eo = (neg ? base - N_EDGES : base) + i16;
        int s = sl[eo];
        int d = dl[eo];
        const unsigned char* ps = xq8 + (size_t)s * 128 + kb * 32;
        const unsigned char* pd = xq8 + (size_t)d * 128 + kb * 32;
        longx2 a01 = *(const longx2*)ps;
        longx2 a23 = *(const longx2*)(ps + 16);
        longx2 b01 = *(const longx2*)pd;
        longx2 b23 = *(const longx2*)(pd + 16);
        floatx4 acc = (floatx4){0.f, 0.f, 0.f, 0.f};
        acc = __builtin_amdgcn_mfma_f32_16x16x32_fp8_fp8(a01[0], b01[0], acc, 0, 0, 0);
        acc = __builtin_amdgcn_mfma_f32_16x16x32_fp8_fp8(a01[1], b01[1], acc, 0, 0, 0);
        acc = __builtin_amdgcn_mfma_f32_16x16x32_fp8_fp8(a23[0], b23[0], acc, 0, 0, 0);
        acc = __builtin_amdgcn_mfma_f32_16x16x32_fp8_fp8(a23[1], b23[1], acc, 0, 0, 0);
        float v = acc[0];
        v = (rsel == 1) ? acc[1] : v;
        v = (rsel == 2) ? acc[2] : v;
        v = (rsel == 3) ? acc[3] : v;
        float dsd = __int_as_float(
            __builtin_amdgcn_ds_bpermute(srcl << 2, __float_as_int(v)));
        if (l < 16) {
            float nv = 0.25f * (n2[s] + n2[d] + 2.f * dsd);
            float vn = fmaxf(sqrtf(fmaxf(nv, 0.f)), EPSV);
            float cs = (0.5f * (a[s] + a[d])) / (vn * qn);
            float sg = neg ? cs : -cs;
            local += log1pf(expf(sg));
        }
    }
    local += __shfl_xor(local, 1, 64);
    local += __shfl_xor(local, 2, 64);
    local += __shfl_xor(local, 4, 64);
    local += __shfl_xor(local, 8, 64);
    __shared__ float sh[4];
    if (l == 0) sh[wvi] = local;
    __syncthreads();
    if (threadIdx.x == 0)
        atomicAdd(lossout, (sh[0] + sh[1] + sh[2] + sh[3]) * (1.f / N_EDGES));
}

// ---------------------------------------------------------------------------
// Launch
// ---------------------------------------------------------------------------

extern "C" void kernel_launch(void* const* d_in, const int* in_sizes, int n_in,
                              void* d_out, int out_size, void* d_ws, size_t ws_size,
                              hipStream_t stream) {
    const int* qp = (const int*)d_in[0];
    const float* feats = (const float*)d_in[1];
    const int* ei = (const int*)d_in[2];
    const int* nei = (const int*)d_in[3];
    const float *w_lq = (const float*)d_in[4], *b_lq = (const float*)d_in[5];
    const float *w_lf = (const float*)d_in[6], *b_lf = (const float*)d_in[7];
    const float *wq0 = (const float*)d_in[8], *bq0 = (const float*)d_in[9];
    const float *wq1 = (const float*)d_in[10], *bq1 = (const float*)d_in[11];
    const float *wq2 = (const float*)d_in[12], *bq2 = (const float*)d_in[13];
    const float *wx0 = (const float*)d_in[14], *bx0 = (const float*)d_in[15];
    const float *wx1 = (const float*)d_in[16], *bx1 = (const float*)d_in[17];
    const float *wx2 = (const float*)d_in[18], *bx2 = (const float*)d_in[19];
    const float *wf0 = (const float*)d_in[20], *bf0 = (const float*)d_in[21];
    const float *wf1 = (const float*)d_in[22], *bf1 = (const float*)d_in[23];
    const float *wf2 = (const float*)d_in[24], *bf2 = (const float*)d_in[25];
    const float *m1w1 = (const float*)d_in[26], *m1b1 = (const float*)d_in[27];
    const float *m1w2 = (const float*)d_in[28], *m1b2 = (const float*)d_in[29];
    const float *m2w1 = (const float*)d_in[30], *m2b1 = (const float*)d_in[31];
    const float *m2w2 = (const float*)d_in[32], *m2b2 = (const float*)d_in[33];
    float* out = (float*)d_out;

    char* p = (char*)d_ws;
    auto alloc = [&](size_t b) -> char* {
        char* r = p;
        p += (b + 255) & ~(size_t)255;
        return r;
    };
    float* dis = (float*)alloc(N_NODES * 4);
    float* inv = (float*)alloc(N_NODES * 4);
    float* t = (float*)alloc(N_NODES * 4);
    float* qe = (float*)alloc(129 * 4);
    float* a = (float*)alloc(N_NODES * 4);
    float* n2 = (float*)alloc(N_NODES * 4);
    float* u1 = (float*)alloc(N_NODES * 4);
    float* u2 = (float*)alloc(N_NODES * 4);
    float* r0v = (float*)alloc(128 * 4);
    float* r1v = (float*)alloc(128 * 4);
    float* g2v = (float*)alloc(128 * 4);
    int* flag = (int*)alloc(4);
    int* cnt = (int*)alloc(N_NODES * 4);
    int* cursor = (int*)alloc(N_NODES * 4);
    int* rowptr = (int*)alloc((N_NODES + 1) * 4);
    int* partial = (int*)alloc(64 * 4);
    int* col = (int*)alloc(N_EDGES * 4);
    int* dstP = (int*)alloc(N_EDGES * 4);
    int* cntN = (int*)alloc(N_NODES * 4);
    int* cursorN = (int*)alloc(N_NODES * 4);
    int* rowptrN = (int*)alloc((N_NODES + 1) * 4);
    int* colN = (int*)alloc(N_EDGES * 4);
    int* dstN = (int*)alloc(N_EDGES * 4);
    unsigned short* Wb = (unsigned short*)alloc((size_t)11 * 16384 * 2);
    unsigned short* featsh = (unsigned short*)alloc((size_t)N_NODES * 128 * 2);
    unsigned short* z0h = (unsigned short*)alloc((size_t)N_NODES * 128 * 2);
    unsigned short* B1h = (unsigned short*)alloc((size_t)N_NODES * 384 * 2);
    unsigned short* B2h = (unsigned short*)alloc((size_t)N_NODES * 384 * 2);
    unsigned char* xq8 = (unsigned char*)alloc((size_t)N_NODES * 128);
    float* xf = (float*)alloc((size_t)N_NODES * 128 * 4);

    const int EB = (N_EDGES + 255) / 256;
    const int NB = (N_NODES + 255) / 256;
    const int NP = (N_NODES + 1023) / 1024;
    const int GB = (N_NODES + 127) / 128;

    hipMemsetAsync(cnt, 0, N_NODES * 4, stream);
    hipMemsetAsync(cursor, 0, N_NODES * 4, stream);
    hipMemsetAsync(cntN, 0, N_NODES * 4, stream);
    hipMemsetAsync(cursorN, 0, N_NODES * 4, stream);
    hipMemsetAsync(t, 0, N_NODES * 4, stream);
    hipMemsetAsync(out + N_NODES, 0, 4, stream);

    // preprocessing: pos CSR (+dst list), deg norms, t vector
    k_count<<<EB, 256, 0, stream>>>(ei, cnt);
    k_invdis<<<NB, 256, 0, stream>>>(cnt, dis, inv);
    k_scan_partial<<<NP, 256, 0, stream>>>(cnt, partial);
    k_scan_mid<<<1, 64, 0, stream>>>(partial, rowptr);
    k_scan_final<<<NP, 256, 0, stream>>>(cnt, partial, rowptr);
    k_fill<<<EB, 256, 0, stream>>>(ei, rowptr, cursor, col, dstP);
    k_t<<<EB, 256, 0, stream>>>(ei, qp, dis, inv, t);
    // neg CSR (dst-sorted neg edge list for the loss)
    k_count<<<EB, 256, 0, stream>>>(nei, cntN);
    k_scan_partial<<<NP, 256, 0, stream>>>(cntN, partial);
    k_scan_mid<<<1, 64, 0, stream>>>(partial, rowptrN);
    k_scan_final<<<NP, 256, 0, stream>>>(cntN, partial, rowptrN);
    k_fill<<<EB, 256, 0, stream>>>(nei, rowptrN, cursorN, colN, dstN);

    k_flag<<<1, 256, 0, stream>>>(bq0, bq1, flag);
    k_cast<<<(N_NODES * 128 / 8 + 255) / 256, 256, 0, stream>>>(feats, featsh,
                                                                N_NODES * 128 / 8);
    WPack wp{{w_lf, wx0, wf0, wq1, wx1, wf1, wq2, wx2, wf2, m1w1, m1w2}};
    k_castw<<<dim3(8, 11), 256, 0, stream>>>(wp, Wb);

    // rank-1 path precompute (gated on flag==1)
    k_r0<<<1, 128, 0, stream>>>(flag, wq0, r0v);
    k_spmv<<<NB, 256, 0, stream>>>(flag, rowptr, col, dis, inv, t, u1);
    k_spmv<<<NB, 256, 0, stream>>>(flag, rowptr, col, dis, inv, u1, u2);
    k_matvec<1><<<128, 64, 0, stream>>>(flag, wq1, r0v, r1v);
    k_matvec<0><<<128, 64, 0, stream>>>(flag, wq2, r1v, g2v);

    // z0 = feats@w_lf.T + b_lf + b_lq (+ w_lq at row q)
    k_gemm<0, 0, 1, 0, 0><<<GB, 256, 0, stream>>>(featsh, 128, Wb + 0 * 16384, b_lf, b_lq,
                                                  nullptr, 0, nullptr, 0,
                                                  nullptr, nullptr, nullptr, 0,
                                                  z0h, 128, nullptr, 0, N_NODES);
    k_addwlq<<<1, 128, 0, stream>>>(qp, w_lq, z0h);

    // layer 0
    k_hq0<<<(N_NODES * 128) / 256, 256, 0, stream>>>(flag, t, wq0, bq0, B1h);
    k_agg<2><<<N_NODES / 4, 256, 0, stream>>>(nullptr, 0, rowptr, col, dis, inv,
                                              featsh, 128, z0h, 128, nullptr, 0,
                                              B2h, 128, 256, 0);
    k_gemm<1, 0, 0, 0, 0><<<GB, 256, 0, stream>>>(B2h + 128, 384, Wb + 1 * 16384, bx0, nullptr,
                                                  nullptr, 0, nullptr, 0,
                                                  nullptr, nullptr, nullptr, 0,
                                                  B1h + 128, 384, nullptr, 0, N_NODES);
    k_gemm<1, 2, 0, 0, 0><<<GB, 256, 0, stream>>>(B2h + 256, 384, Wb + 2 * 16384, bf0, nullptr,
                                                  B1h + 0, 384, B1h + 128, 384,
                                                  nullptr, nullptr, flag, 0,
                                                  B1h + 256, 384, nullptr, 0, N_NODES);
    k_gemm<1, 1, 0, 0, 1><<<GB, 256, 0, stream>>>(B2h + 256, 384, Wb + 2 * 16384, bf0, nullptr,
                                                  B1h + 128, 384, nullptr, 0,
                                                  t, r0v, flag, 1,
                                                  B1h + 256, 384, nullptr, 0, N_NODES);

    // layer 1
    k_agg<3><<<N_NODES / 4, 256, 0, stream>>>(flag, 0, rowptr, col, dis, inv,
                                              B1h, 384, B1h + 128, 384, B1h + 256, 384,
                                              B2h, 0, 128, 256);
    k_agg<2><<<N_NODES / 4, 256, 0, stream>>>(flag, 1, rowptr, col, dis, inv,
                                              B1h + 128, 384, B1h + 256, 384, nullptr, 0,
                                              B2h, 128, 256, 0);
    k_gemm<1, 0, 0, 0, 0><<<GB, 256, 0, stream>>>(B2h + 0, 384, Wb + 3 * 16384, bq1, nullptr,
                                                  nullptr, 0, nullptr, 0,
                                                  nullptr, nullptr, flag, 0,
                                                  B1h + 0, 384, nullptr, 0, N_NODES);
    k_gemm<1, 0, 0, 0, 0><<<GB, 256, 0, stream>>>(B2h + 128, 384, Wb + 4 * 16384, bx1, nullptr,
                                                  nullptr, 0, nullptr, 0,
                                                  nullptr, nullptr, nullptr, 0,
                                                  B1h + 128, 384, nullptr, 0, N_NODES);
    k_gemm<1, 2, 0, 0, 0><<<GB, 256, 0, stream>>>(B2h + 256, 384, Wb + 5 * 16384, bf1, nullptr,
                                                  B1h + 0, 384, B1h + 128, 384,
                                                  nullptr, nullptr, flag, 0,
                                                  B1h + 256, 384, nullptr, 0, N_NODES);
    k_gemm<1, 1, 0, 0, 1><<<GB, 256, 0, stream>>>(B2h + 256, 384, Wb + 5 * 16384, bf1, nullptr,
                                                  B1h + 128, 384, nullptr, 0,
                                                  u1, r1v, flag, 1,
                                                  B1h + 256, 384, nullptr, 0, N_NODES);

    // layer 2 (no relu)
    k_agg<3><<<N_NODES / 4, 256, 0, stream>>>(flag, 0, rowptr, col, dis, inv,
                                              B1h, 384, B1h + 128, 384, B1h + 256, 384,
                                              B2h, 0, 128, 256);
    k_agg<2><<<N_NODES / 4, 256, 0, stream>>>(flag, 1, rowptr, col, dis, inv,
                                              B1h + 128, 384, B1h + 256, 384, nullptr, 0,
                                              B2h, 128, 256, 0);
    k_gemm<0, 0, 0, 0, 0><<<GB, 256, 0, stream>>>(B2h + 0, 384, Wb + 6 * 16384, bq2, nullptr,
                                                  nullptr, 0, nullptr, 0,
                                                  nullptr, nullptr, flag, 0,
                                                  B1h + 0, 384, nullptr, 0, N_NODES);
    k_gemm<0, 0, 0, 0, 0><<<GB, 256, 0, stream>>>(B2h + 128, 384, Wb + 7 * 16384, bx2, nullptr,
                                                  nullptr, 0, nullptr, 0,
                                                  nullptr, nullptr, nullptr, 0,
                                                  B1h + 128, 384, nullptr, 0, N_NODES);
    k_gemm<0, 2, 0, 0, 0><<<GB, 256, 0, stream>>>(B2h + 256, 384, Wb + 8 * 16384, bf2, nullptr,
                                                  B1h + 0, 384, B1h + 128, 384,
                                                  nullptr, nullptr, flag, 0,
                                                  B1h + 256, 384, nullptr, 0, N_NODES);
    k_gemm<0, 1, 1, 0, 1><<<GB, 256, 0, stream>>>(B2h + 256, 384, Wb + 8 * 16384, bf2, bq2,
                                                  B1h + 128, 384, nullptr, 0,
                                                  u2, g2v, flag, 1,
                                                  B1h + 256, 384, nullptr, 0, N_NODES);

    // mlp1
    k_gemm<1, 0, 0, 0, 0><<<GB, 256, 0, stream>>>(B1h + 256, 384, Wb + 9 * 16384, m1b1, nullptr,
                                                  nullptr, 0, nullptr, 0,
                                                  nullptr, nullptr, nullptr, 0,
                                                  B2h + 0, 384, nullptr, 0, N_NODES);
    k_gemm<0, 0, 0, 1, 0><<<GB, 256, 0, stream>>>(B2h + 0, 384, Wb + 10 * 16384, m1b2, nullptr,
                                                  nullptr, 0, nullptr, 0,
                                                  nullptr, nullptr, nullptr, 0,
                                                  nullptr, 0, xf, 128, N_NODES);

    // decode
    k_cast8<<<(N_NODES * 8 + 255) / 256, 256, 0, stream>>>(xf, xq8);
    k_qemb<<<1, 128, 0, stream>>>(qp, xf, qe);
    k_node<<<N_NODES / 4, 256, 0, stream>>>(xf, qe, m2w1, m2b1, m2w2, m2b2, out, a, n2);
    k_loss<<<2048, 256, 0, stream>>>(col, dstP, colN, dstN, xq8, a, n2, qe, out + N_NODES);
}

// Round 12
// 611.715 us; speedup vs baseline: 1.1419x; 1.1419x over previous
//
#include <hip/hip_runtime.h>
#include <math.h>

#define N_NODES 50000
#define N_EDGES 800000
#define EPSV 1e-8f
#define ALPHA 0.3f

typedef __attribute__((ext_vector_type(8))) unsigned short ushort8;
typedef __attribute__((ext_vector_type(4))) float floatx4;
typedef __attribute__((ext_vector_type(2))) long longx2;
typedef _Float16 half8 __attribute__((ext_vector_type(8)));
typedef _Float16 half2v __attribute__((ext_vector_type(2)));

__device__ inline unsigned short f2h(float f) {
    union { _Float16 h; unsigned short u; } c; c.h = (_Float16)f; return c.u;
}
__device__ inline float h2f(unsigned short u) {
    union { unsigned short u; _Float16 h; } c; c.u = u; return (float)c.h;
}
// fp32 -> OCP e4m3fn, round-nearest-even, saturating at 448
__device__ inline unsigned char f2e4m3(float f) {
    unsigned u = __float_as_uint(f);
    unsigned s = (u >> 24) & 0x80u;
    float af = fabsf(f);
    if (af >= 464.f) return (unsigned char)(s | 0x7Eu);
    if (af < 0.015625f) {
        int m = (int)rintf(af * 512.f);
        return (unsigned char)(s | (unsigned)m);
    }
    unsigned au = __float_as_uint(af);
    unsigned mant = au & 0x7FFFFFu;
    unsigned lsb = (mant >> 20) & 1u;
    mant += 0x7FFFFu + lsb;
    unsigned exp32 = (au >> 23) + (mant >> 23);
    mant &= 0x7FFFFFu;
    unsigned e8 = exp32 - 127u + 7u;
    return (unsigned char)(s | (e8 << 3) | (mant >> 20));
}

// ---------------------------------------------------------------------------
// Graph preprocessing
// ---------------------------------------------------------------------------

__global__ __launch_bounds__(256) void k_count(const int* __restrict__ ei,
                                               int* __restrict__ cnt) {
    int e = blockIdx.x * 256 + threadIdx.x;
    if (e < N_EDGES) atomicAdd(&cnt[ei[N_EDGES + e]], 1);
}

__global__ __launch_bounds__(256) void k_invdis(const int* __restrict__ cnt,
                                                float* __restrict__ dis,
                                                float* __restrict__ inv) {
    int i = blockIdx.x * 256 + threadIdx.x;
    if (i < N_NODES) {
        float d = (float)cnt[i] + 1.0f;
        dis[i] = 1.0f / sqrtf(d);
        inv[i] = 1.0f / d;
    }
}

__global__ __launch_bounds__(256) void k_scan_partial(const int* __restrict__ cnt,
                                                      int* __restrict__ partial) {
    int b = blockIdx.x, t = threadIdx.x;
    int base = b * 1024 + t * 4;
    int s = 0;
#pragma unroll
    for (int j = 0; j < 4; ++j) {
        int idx = base + j;
        if (idx < N_NODES) s += cnt[idx];
    }
#pragma unroll
    for (int m = 1; m < 64; m <<= 1) s += __shfl_xor(s, m, 64);
    __shared__ int sh[4];
    if ((t & 63) == 0) sh[t >> 6] = s;
    __syncthreads();
    if (t == 0) partial[b] = sh[0] + sh[1] + sh[2] + sh[3];
}

__global__ void k_scan_mid(int* __restrict__ partial, int* __restrict__ rowptr) {
    int l = threadIdx.x;
    const int NP = (N_NODES + 1023) / 1024;
    int v = (l < NP) ? partial[l] : 0;
    int vin = v;
#pragma unroll
    for (int off = 1; off < 64; off <<= 1) {
        int u = __shfl_up(v, off, 64);
        if (l >= off) v += u;
    }
    if (l < NP) partial[l] = v - vin;
    if (l == NP - 1) rowptr[N_NODES] = v;
}

__global__ __launch_bounds__(256) void k_scan_final(const int* __restrict__ cnt,
                                                    const int* __restrict__ partial,
                                                    int* __restrict__ rowptr) {
    int b = blockIdx.x, t = threadIdx.x;
    int base = b * 1024 + t * 4;
    int c[4];
    int s = 0;
#pragma unroll
    for (int j = 0; j < 4; ++j) {
        int idx = base + j;
        c[j] = (idx < N_NODES) ? cnt[idx] : 0;
        s += c[j];
    }
    __shared__ int sh[256];
    sh[t] = s;
    __syncthreads();
    for (int off = 1; off < 256; off <<= 1) {
        int v = 0;
        if (t >= off) v = sh[t - off];
        __syncthreads();
        sh[t] += v;
        __syncthreads();
    }
    int texcl = sh[t] - s;
    int pre = partial[b] + texcl;
#pragma unroll
    for (int j = 0; j < 4; ++j) {
        int idx = base + j;
        if (idx < N_NODES) rowptr[idx] = pre;
        pre += c[j];
    }
}

__global__ __launch_bounds__(256) void k_fill(const int* __restrict__ ei,
                                              const int* __restrict__ rowptr,
                                              int* __restrict__ cursor,
                                              int* __restrict__ col) {
    int e = blockIdx.x * 256 + threadIdx.x;
    if (e < N_EDGES) {
        int d = ei[N_EDGES + e];
        int pos = rowptr[d] + atomicAdd(&cursor[d], 1);
        col[pos] = ei[e];
    }
}

__global__ __launch_bounds__(256) void k_t(const int* __restrict__ ei,
                                           const int* __restrict__ qp,
                                           const float* __restrict__ dis,
                                           const float* __restrict__ inv,
                                           float* __restrict__ t) {
    int e = blockIdx.x * 256 + threadIdx.x;
    int q = *qp;
    if (e == 0) atomicAdd(&t[q], inv[q]);
    if (e < N_EDGES && ei[e] == q) {
        int d = ei[N_EDGES + e];
        atomicAdd(&t[d], dis[q] * dis[d]);
    }
}

// flag = 1 iff bq0 and bq1 are all-zero (enables exact rank-1 hq tower)
__global__ void k_flag(const float* __restrict__ bq0, const float* __restrict__ bq1,
                       int* __restrict__ flag) {
    int j = threadIdx.x;  // 256
    float v = (j < 128) ? bq0[j] : bq1[j - 128];
    unsigned long long b = __ballot(v != 0.f);
    __shared__ int bad[4];
    if ((j & 63) == 0) bad[j >> 6] = (b != 0ull);
    __syncthreads();
    if (j == 0) flag[0] = !(bad[0] | bad[1] | bad[2] | bad[3]);
}

// r0 = relu(wq0)   [rank-1 path]
__global__ void k_r0(const int* __restrict__ gflag, const float* __restrict__ wq0,
                     float* __restrict__ r0) {
    if (*gflag != 1) return;
    int j = threadIdx.x;  // 128
    r0[j] = fmaxf(wq0[j], 0.f);
}

// vout[c] = (relu?)( sum_k W[c][k]*vin[k] )   [rank-1 path, gated]
template <int RELU>
__global__ void k_matvec(const int* __restrict__ gflag, const float* __restrict__ W,
                         const float* __restrict__ vin, float* __restrict__ vout) {
    if (*gflag != 1) return;
    int c = blockIdx.x, l = threadIdx.x;  // 128 blocks x 64
    float2 w = *(const float2*)(W + c * 128 + 2 * l);
    float2 v = *(const float2*)(vin + 2 * l);
    float s = w.x * v.x + w.y * v.y;
#pragma unroll
    for (int m = 1; m < 64; m <<= 1) s += __shfl_xor(s, m, 64);
    if (l == 0) vout[c] = RELU ? fmaxf(s, 0.f) : s;
}

// vout = Ahat * vin  (scalar SpMV)   [rank-1 path, gated]
__global__ __launch_bounds__(256) void k_spmv(const int* __restrict__ gflag,
                                              const int* __restrict__ rowptr,
                                              const int* __restrict__ col,
                                              const float* __restrict__ dis,
                                              const float* __restrict__ inv,
                                              const float* __restrict__ vin,
                                              float* __restrict__ vout) {
    if (*gflag != 1) return;
    int i = blockIdx.x * 256 + threadIdx.x;
    if (i >= N_NODES) return;
    int r0 = rowptr[i], r1 = rowptr[i + 1];
    float s = 0.f;
    for (int e = r0; e < r1; ++e) {
        int c = col[e];
        s += dis[c] * vin[c];
    }
    vout[i] = fmaf(inv[i], vin[i], dis[i] * s);
}

// fp32 -> fp16 cast
__global__ __launch_bounds__(256) void k_cast(const float* __restrict__ in,
                                              unsigned short* __restrict__ out, int n8) {
    int id = blockIdx.x * 256 + threadIdx.x;
    if (id >= n8) return;
    const float4 a = *(const float4*)(in + id * 8);
    const float4 b = *(const float4*)(in + id * 8 + 4);
    ushort8 o;
    o[0] = f2h(a.x); o[1] = f2h(a.y); o[2] = f2h(a.z); o[3] = f2h(a.w);
    o[4] = f2h(b.x); o[5] = f2h(b.y); o[6] = f2h(b.z); o[7] = f2h(b.w);
    *(ushort8*)(out + id * 8) = o;
}

struct WPack { const float* w[11]; };
__global__ __launch_bounds__(256) void k_castw(WPack wp, unsigned short* __restrict__ out) {
    int m = blockIdx.y;
    int id = blockIdx.x * 256 + threadIdx.x;
    const float* src = wp.w[m] + id * 8;
    float4 a = *(const float4*)src;
    float4 b = *(const float4*)(src + 4);
    ushort8 o;
    o[0] = f2h(a.x); o[1] = f2h(a.y); o[2] = f2h(a.z); o[3] = f2h(a.w);
    o[4] = f2h(b.x); o[5] = f2h(b.y); o[6] = f2h(b.z); o[7] = f2h(b.w);
    *(ushort8*)(out + m * 16384 + id * 8) = o;
}

// xf -> fp8 table, permuted: byte p = kb*32 + m*8 + j  holds value k = m*32 + kb*8 + j
__global__ __launch_bounds__(256) void k_cast8(const float* __restrict__ xf,
                                               unsigned char* __restrict__ xq8) {
    int id = blockIdx.x * 256 + threadIdx.x;
    int node = id >> 3, c = id & 7;
    if (node >= N_NODES) return;
    int kb = c >> 1, mb = (c & 1) * 2;
    const float* base = xf + (size_t)node * 128;
    const float* p0 = base + mb * 32 + kb * 8;
    const float* p1 = base + (mb + 1) * 32 + kb * 8;
    union { unsigned char b[16]; uint4 u; } o;
#pragma unroll
    for (int j = 0; j < 8; ++j) o.b[j] = f2e4m3(p0[j]);
#pragma unroll
    for (int j = 0; j < 8; ++j) o.b[8 + j] = f2e4m3(p1[j]);
    *(uint4*)(xq8 + (size_t)node * 128 + c * 16) = o.u;
}

// ---------------------------------------------------------------------------
// MFMA fp16 GEMM, A/W staged via global_load_lds (pre-swizzled source).
// ---------------------------------------------------------------------------

template <int RELU, int NADD, int HASB2, int WOUT, int RK1>
__global__ __launch_bounds__(256) void k_gemm(
    const unsigned short* __restrict__ A, int As,
    const unsigned short* __restrict__ Wb,
    const float* __restrict__ bias, const float* __restrict__ bias2,
    const unsigned short* __restrict__ add1, int a1s,
    const unsigned short* __restrict__ add2, int a2s,
    const float* __restrict__ u, const float* __restrict__ vq,
    const int* __restrict__ gflag, int want,
    unsigned short* __restrict__ outh, int ohs,
    float* __restrict__ outf, int ofs, int nrows) {
    if (gflag && *gflag != want) return;
    __shared__ unsigned short Al[128 * 128];
    __shared__ unsigned short Wl[128 * 128];
    const int tid = threadIdx.x;
    const int row0 = blockIdx.x * 128;
    const int wv = tid >> 6;
    const int t4 = tid >> 4, c16 = tid & 15;

#pragma unroll
    for (int it = 0; it < 8; ++it) {
        int r = it * 16 + t4;
        int gr = row0 + r; if (gr > nrows - 1) gr = nrows - 1;
        int sw = (c16 * 16) ^ ((r & 7) << 4);
        const char* srcA = (const char*)(A + (size_t)gr * As) + sw;
        __builtin_amdgcn_global_load_lds(
            (const __attribute__((address_space(1))) void*)srcA,
            (__attribute__((address_space(3))) void*)(Al + it * 2048 + wv * 512),
            16, 0, 0);
        const char* srcW = (const char*)(Wb + r * 128) + sw;
        __builtin_amdgcn_global_load_lds(
            (const __attribute__((address_space(1))) void*)srcW,
            (__attribute__((address_space(3))) void*)(Wl + it * 2048 + wv * 512),
            16, 0, 0);
    }
    __syncthreads();

    const int l = tid & 63;
    const int lr = l & 15, lg = l >> 4;
    const int sx = (lr & 7) << 4;

    floatx4 acc[8][2];
#pragma unroll
    for (int i = 0; i < 8; ++i)
#pragma unroll
        for (int j = 0; j < 2; ++j) acc[i][j] = (floatx4){0.f, 0.f, 0.f, 0.f};

#pragma unroll
    for (int ks = 0; ks < 4; ++ks) {
        int ko = (ks * 64 + lg * 16) ^ sx;
        half8 bfr[2];
#pragma unroll
        for (int ct = 0; ct < 2; ++ct) {
            int c = wv * 32 + ct * 16 + lr;
            bfr[ct] = *(const half8*)((char*)Wl + c * 256 + ko);
        }
#pragma unroll
        for (int rt = 0; rt < 8; ++rt) {
            int r = rt * 16 + lr;
            half8 af = *(const half8*)((char*)Al + r * 256 + ko);
            acc[rt][0] = __builtin_amdgcn_mfma_f32_16x16x32_f16(af, bfr[0], acc[rt][0], 0, 0, 0);
            acc[rt][1] = __builtin_amdgcn_mfma_f32_16x16x32_f16(af, bfr[1], acc[rt][1], 0, 0, 0);
        }
    }

    // C/D layout: col=lane&15, row=(lane>>4)*4+reg
#pragma unroll
    for (int ct = 0; ct < 2; ++ct) {
        int colc = wv * 32 + ct * 16 + lr;
        float bv = bias[colc];
        if (HASB2) bv += bias2[colc];
        float vqc = RK1 ? vq[colc] : 0.f;
#pragma unroll
        for (int rt = 0; rt < 8; ++rt) {
            int rbase = row0 + rt * 16 + lg * 4;
#pragma unroll
            for (int reg = 0; reg < 4; ++reg) {
                int r = rbase + reg;
                if (r >= nrows) continue;
                float v = acc[rt][ct][reg] + bv;
                if (RK1) v = fmaf(u[r], vqc, v);
                if (NADD >= 1) v += h2f(add1[(size_t)r * a1s + colc]);
                if (NADD >= 2) v += h2f(add2[(size_t)r * a2s + colc]);
                if (RELU) v = fmaxf(v, 0.f);
                if (WOUT) outf[(size_t)r * ofs + colc] = v;
                else outh[(size_t)r * ohs + colc] = f2h(v);
            }
        }
    }
}

// ---------------------------------------------------------------------------
// SpMM, fp16 packed-FMA accumulate, NUM streams, edge loop unrolled x2
// (8 edges in flight per wave) with dual accumulator sets.
// ---------------------------------------------------------------------------

template <int NUM>
__global__ __launch_bounds__(256) void k_agg(
    const int* __restrict__ gflag, int want,
    const int* __restrict__ rowptr, const int* __restrict__ col,
    const float* __restrict__ dis, const float* __restrict__ inv,
    const unsigned short* __restrict__ in0, int s0,
    const unsigned short* __restrict__ in1, int s1,
    const unsigned short* __restrict__ in2, int s2,
    unsigned short* __restrict__ out, int o0, int o1, int o2) {
    if (gflag && *gflag != want) return;
    int i = blockIdx.x * 4 + (threadIdx.x >> 6);
    int l = threadIdx.x & 63;
    int g = l >> 4, li = l & 15;
    int r0 = rowptr[i], r1 = rowptr[i + 1];

    half2v accA[NUM][4], accB[NUM][4];
#pragma unroll
    for (int b = 0; b < NUM; ++b)
#pragma unroll
        for (int j = 0; j < 4; ++j) {
            accA[b][j] = (half2v){(_Float16)0, (_Float16)0};
            accB[b][j] = (half2v){(_Float16)0, (_Float16)0};
        }

    union U8 { ushort8 u; half2v h[4]; };
    const unsigned short* ins[3] = {in0, in1, in2};
    const int ss[3] = {s0, s1, s2};

    for (int base = r0; base < r1; base += 8) {
        int eA = base + g, eB = base + 4 + g;
        int sA = i; float wA = 0.f;
        if (eA < r1) { sA = col[eA]; wA = dis[sA]; }
        int sB = i; float wB = 0.f;
        if (eB < r1) { sB = col[eB]; wB = dis[sB]; }
        _Float16 whA = (_Float16)wA, whB = (_Float16)wB;
        half2v w2A = {whA, whA}, w2B = {whB, whB};
        U8 vA[NUM], vB[NUM];
#pragma unroll
        for (int b = 0; b < NUM; ++b) {
            vA[b].u = *(const ushort8*)(ins[b] + (size_t)sA * ss[b] + li * 8);
            vB[b].u = *(const ushort8*)(ins[b] + (size_t)sB * ss[b] + li * 8);
        }
#pragma unroll
        for (int b = 0; b < NUM; ++b)
#pragma unroll
            for (int j = 0; j < 4; ++j) {
                accA[b][j] += vA[b].h[j] * w2A;
                accB[b][j] += vB[b].h[j] * w2B;
            }
    }
    union U2 { half2v h; int i; };
#pragma unroll
    for (int b = 0; b < NUM; ++b)
#pragma unroll
        for (int j = 0; j < 4; ++j) {
            U2 c, o;
            c.h = accA[b][j] + accB[b][j];
            o.i = __shfl_xor(c.i, 16, 64); c.h += o.h;
            o.i = __shfl_xor(c.i, 32, 64); c.h += o.h;
            accA[b][j] = c.h;
        }
    if (g == 0) {
        float di = dis[i], iv = inv[i];
        const int oo[3] = {o0, o1, o2};
#pragma unroll
        for (int b = 0; b < NUM; ++b) {
            U8 sv;
            sv.u = *(const ushort8*)(ins[b] + (size_t)i * ss[b] + li * 8);
            ushort8 o;
#pragma unroll
            for (int j = 0; j < 4; ++j) {
                float a0 = fmaf(di, (float)accA[b][j][0], iv * (float)sv.h[j][0]);
                float a1 = fmaf(di, (float)accA[b][j][1], iv * (float)sv.h[j][1]);
                o[2 * j] = f2h(a0);
                o[2 * j + 1] = f2h(a1);
            }
            *(ushort8*)(out + (size_t)i * 384 + oo[b] + li * 8) = o;
        }
    }
}

// hq0[i][j] = relu(t[i]*wq0[j] + bq0[j])   [full path only]
__global__ __launch_bounds__(256) void k_hq0(const int* __restrict__ gflag,
                                             const float* __restrict__ t,
                                             const float* __restrict__ wq0,
                                             const float* __restrict__ bq0,
                                             unsigned short* __restrict__ B1h) {
    if (*gflag != 0) return;
    int gidx = blockIdx.x * 256 + threadIdx.x;
    int i = gidx >> 7, j = gidx & 127;
    B1h[(size_t)i * 384 + j] = f2h(fmaxf(fmaf(t[i], wq0[j], bq0[j]), 0.f));
}

__global__ void k_addwlq(const int* __restrict__ qp, const float* __restrict__ w_lq,
                         unsigned short* __restrict__ z0h) {
    int j = threadIdx.x;
    int q = *qp;
    z0h[(size_t)q * 128 + j] = f2h(h2f(z0h[(size_t)q * 128 + j]) + w_lq[j]);
}

// ---------------------------------------------------------------------------
// Decode
// ---------------------------------------------------------------------------

__global__ void k_qemb(const int* __restrict__ qp, const float* __restrict__ xf,
                       float* __restrict__ qe) {
    int j = threadIdx.x;  // 128
    int q = *qp;
    float v = xf[(size_t)q * 128 + j];
    qe[j] = v;
    float s = v * v;
#pragma unroll
    for (int m = 1; m < 64; m <<= 1) s += __shfl_xor(s, m, 64);
    __shared__ float sh[2];
    if ((j & 63) == 0) sh[j >> 6] = s;
    __syncthreads();
    if (j == 0) qe[128] = fmaxf(sqrtf(sh[0] + sh[1]), EPSV);
}

__global__ __launch_bounds__(256) void k_node(const float* __restrict__ xf,
                                              const float* __restrict__ qe,
                                              const float* __restrict__ m2w1,
                                              const float* __restrict__ m2b1,
                                              const float* __restrict__ m2w2,
                                              const float* __restrict__ m2b2,
                                              float* __restrict__ out,
                                              float* __restrict__ a,
                                              float* __restrict__ n2) {
    int node = blockIdx.x * 4 + (threadIdx.x >> 6);
    int lane = threadIdx.x & 63;
    const float2 xv = *(const float2*)(xf + (size_t)node * 128 + 2 * lane);
    const float2 qv = *(const float2*)(qe + 2 * lane);
    const float2 wv = *(const float2*)(m2w1 + 2 * lane);
    float dq = xv.x * qv.x + xv.y * qv.y;
    float dx = xv.x * xv.x + xv.y * xv.y;
    float dw = xv.x * wv.x + xv.y * wv.y;
#pragma unroll
    for (int m = 1; m < 64; m <<= 1) {
        dq += __shfl_xor(dq, m, 64);
        dx += __shfl_xor(dx, m, 64);
        dw += __shfl_xor(dw, m, 64);
    }
    if (lane == 0) {
        float qn = qe[128];
        float vn = fmaxf(sqrtf(dx), EPSV);
        float simq = dq / (vn * qn);
        float l1 = dw + m2b1[0];
        float s2 = fmaxf(l1, 0.f) * m2w2[0] + m2b2[0];
        float sim = ((1.f - ALPHA) * simq + ALPHA * s2) * 2.f;
        out[node] = 1.f / (1.f + expf(-sim));
        a[node] = dq;
        n2[node] = dx;
    }
}

// fused pos+neg edge BCE via fp8 MFMA-diag, 2-tile software pipeline.
__global__ __launch_bounds__(256) void k_loss(const int* __restrict__ ei,
                                              const int* __restrict__ nei,
                                              const unsigned char* __restrict__ xq8,
                                              const float* __restrict__ a,
                                              const float* __restrict__ n2,
                                              const float* __restrict__ qe,
                                              float* __restrict__ lossout) {
    int l = threadIdx.x & 63, wvi = threadIdx.x >> 6;
    int i16 = l & 15;
    int kb = l >> 4;
    int gw = blockIdx.x * 4 + wvi;
    const int NW = gridDim.x * 4;
    const int NT = 2 * N_EDGES / 16;  // 100000 tiles, each purely pos or neg
    float qn = qe[128];
    float local = 0.f;

    int t = gw;
    for (; t + NW < NT; t += 2 * NW) {
        // ---------------- load phase: tiles A (t) and B (t+NW) ----------------
        int baseA = t * 16;
        int negA = baseA >= N_EDGES;
        const int* EpA = negA ? nei : ei;
        int eoA = negA ? baseA - N_EDGES : baseA;
        int sA = EpA[eoA + i16], dA = EpA[eoA + i16 + N_EDGES];

        int baseB = (t + NW) * 16;
        int negB = baseB >= N_EDGES;
        const int* EpB = negB ? nei : ei;
        int eoB = negB ? baseB - N_EDGES : baseB;
        int sB = EpB[eoB + i16], dB = EpB[eoB + i16 + N_EDGES];

        const unsigned char* psA = xq8 + (size_t)sA * 128 + kb * 32;
        const unsigned char* pdA = xq8 + (size_t)dA * 128 + kb * 32;
        longx2 a01A = *(const longx2*)psA;
        longx2 a23A = *(const longx2*)(psA + 16);
        longx2 b01A = *(const longx2*)pdA;
        longx2 b23A = *(const longx2*)(pdA + 16);

        const unsigned char* psB = xq8 + (size_t)sB * 128 + kb * 32;
        const unsigned char* pdB = xq8 + (size_t)dB * 128 + kb * 32;
        longx2 a01B = *(const longx2*)psB;
        longx2 a23B = *(const longx2*)(psB + 16);
        longx2 b01B = *(const longx2*)pdB;
        longx2 b23B = *(const longx2*)(pdB + 16);

        float n2sA = 0.f, n2dA = 0.f, asA = 0.f, adA = 0.f;
        float n2sB = 0.f, n2dB = 0.f, asB = 0.f, adB = 0.f;
        if (l < 16) {
            n2sA = n2[sA]; n2dA = n2[dA]; asA = a[sA]; adA = a[dA];
            n2sB = n2[sB]; n2dB = n2[dB]; asB = a[sB]; adB = a[dB];
        }

        // ---------------- compute phase ----------------
        int r = l & 3;
        int srcl = ((i16 >> 2) << 4) + i16;
        {
            floatx4 acc = (floatx4){0.f, 0.f, 0.f, 0.f};
            acc = __builtin_amdgcn_mfma_f32_16x16x32_fp8_fp8(a01A[0], b01A[0], acc, 0, 0, 0);
            acc = __builtin_amdgcn_mfma_f32_16x16x32_fp8_fp8(a01A[1], b01A[1], acc, 0, 0, 0);
            acc = __builtin_amdgcn_mfma_f32_16x16x32_fp8_fp8(a23A[0], b23A[0], acc, 0, 0, 0);
            acc = __builtin_amdgcn_mfma_f32_16x16x32_fp8_fp8(a23A[1], b23A[1], acc, 0, 0, 0);
            float v = acc[0];
            v = (r == 1) ? acc[1] : v;
            v = (r == 2) ? acc[2] : v;
            v = (r == 3) ? acc[3] : v;
            float dsd = __int_as_float(
                __builtin_amdgcn_ds_bpermute(srcl << 2, __float_as_int(v)));
            if (l < 16) {
                float nv = 0.25f * (n2sA + n2dA + 2.f * dsd);
                float vn = fmaxf(sqrtf(fmaxf(nv, 0.f)), EPSV);
                float cs = (0.5f * (asA + adA)) / (vn * qn);
                float sg = negA ? cs : -cs;
                local += log1pf(expf(sg));
            }
        }
        {
            floatx4 acc = (floatx4){0.f, 0.f, 0.f, 0.f};
            acc = __builtin_amdgcn_mfma_f32_16x16x32_fp8_fp8(a01B[0], b01B[0], acc, 0, 0, 0);
            acc = __builtin_amdgcn_mfma_f32_16x16x32_fp8_fp8(a01B[1], b01B[1], acc, 0, 0, 0);
            acc = __builtin_amdgcn_mfma_f32_16x16x32_fp8_fp8(a23B[0], b23B[0], acc, 0, 0, 0);
            acc = __builtin_amdgcn_mfma_f32_16x16x32_fp8_fp8(a23B[1], b23B[1], acc, 0, 0, 0);
            float v = acc[0];
            v = (r == 1) ? acc[1] : v;
            v = (r == 2) ? acc[2] : v;
            v = (r == 3) ? acc[3] : v;
            float dsd = __int_as_float(
                __builtin_amdgcn_ds_bpermute(srcl << 2, __float_as_int(v)));
            if (l < 16) {
                float nv = 0.25f * (n2sB + n2dB + 2.f * dsd);
                float vn = fmaxf(sqrtf(fmaxf(nv, 0.f)), EPSV);
                float cs = (0.5f * (asB + adB)) / (vn * qn);
                float sg = negB ? cs : -cs;
                local += log1pf(expf(sg));
            }
        }
    }
    if (t < NT) {  // remainder tile
        int base = t * 16;
        int neg = base >= N_EDGES;
        const int* Ep = neg ? nei : ei;
        int eo = neg ? base - N_EDGES : base;
        int s = Ep[eo + i16], d = Ep[eo + i16 + N_EDGES];
        const unsigned char* ps = xq8 + (size_t)s * 128 + kb * 32;
        const unsigned char* pd = xq8 + (size_t)d * 128 + kb * 32;
        longx2 a01 = *(const longx2*)ps;
        longx2 a23 = *(const longx2*)(ps + 16);
        longx2 b01 = *(const longx2*)pd;
        longx2 b23 = *(const longx2*)(pd + 16);
        floatx4 acc = (floatx4){0.f, 0.f, 0.f, 0.f};
        acc = __builtin_amdgcn_mfma_f32_16x16x32_fp8_fp8(a01[0], b01[0], acc, 0, 0, 0);
        acc = __builtin_amdgcn_mfma_f32_16x16x32_fp8_fp8(a01[1], b01[1], acc, 0, 0, 0);
        acc = __builtin_amdgcn_mfma_f32_16x16x32_fp8_fp8(a23[0], b23[0], acc, 0, 0, 0);
        acc = __builtin_amdgcn_mfma_f32_16x16x32_fp8_fp8(a23[1], b23[1], acc, 0, 0, 0);
        int r = l & 3;
        float v = acc[0];
        v = (r == 1) ? acc[1] : v;
        v = (r == 2) ? acc[2] : v;
        v = (r == 3) ? acc[3] : v;
        int srcl = ((i16 >> 2) << 4) + i16;
        float dsd = __int_as_float(
            __builtin_amdgcn_ds_bpermute(srcl << 2, __float_as_int(v)));
        if (l < 16) {
            float nv = 0.25f * (n2[s] + n2[d] + 2.f * dsd);
            float vn = fmaxf(sqrtf(fmaxf(nv, 0.f)), EPSV);
            float cs = (0.5f * (a[s] + a[d])) / (vn * qn);
            float sg = neg ? cs : -cs;
            local += log1pf(expf(sg));
        }
    }
    local += __shfl_xor(local, 1, 64);
    local += __shfl_xor(local, 2, 64);
    local += __shfl_xor(local, 4, 64);
    local += __shfl_xor(local, 8, 64);
    __shared__ float sh[4];
    if (l == 0) sh[wvi] = local;
    __syncthreads();
    if (threadIdx.x == 0)
        atomicAdd(lossout, (sh[0] + sh[1] + sh[2] + sh[3]) * (1.f / N_EDGES));
}

// ---------------------------------------------------------------------------
// Launch
// ---------------------------------------------------------------------------

extern "C" void kernel_launch(void* const* d_in, const int* in_sizes, int n_in,
                              void* d_out, int out_size, void* d_ws, size_t ws_size,
                              hipStream_t stream) {
    const int* qp = (const int*)d_in[0];
    const float* feats = (const float*)d_in[1];
    const int* ei = (const int*)d_in[2];
    const int* nei = (const int*)d_in[3];
    const float *w_lq = (const float*)d_in[4], *b_lq = (const float*)d_in[5];
    const float *w_lf = (const float*)d_in[6], *b_lf = (const float*)d_in[7];
    const float *wq0 = (const float*)d_in[8], *bq0 = (const float*)d_in[9];
    const float *wq1 = (const float*)d_in[10], *bq1 = (const float*)d_in[11];
    const float *wq2 = (const float*)d_in[12], *bq2 = (const float*)d_in[13];
    const float *wx0 = (const float*)d_in[14], *bx0 = (const float*)d_in[15];
    const float *wx1 = (const float*)d_in[16], *bx1 = (const float*)d_in[17];
    const float *wx2 = (const float*)d_in[18], *bx2 = (const float*)d_in[19];
    const float *wf0 = (const float*)d_in[20], *bf0 = (const float*)d_in[21];
    const float *wf1 = (const float*)d_in[22], *bf1 = (const float*)d_in[23];
    const float *wf2 = (const float*)d_in[24], *bf2 = (const float*)d_in[25];
    const float *m1w1 = (const float*)d_in[26], *m1b1 = (const float*)d_in[27];
    const float *m1w2 = (const float*)d_in[28], *m1b2 = (const float*)d_in[29];
    const float *m2w1 = (const float*)d_in[30], *m2b1 = (const float*)d_in[31];
    const float *m2w2 = (const float*)d_in[32], *m2b2 = (const float*)d_in[33];
    float* out = (float*)d_out;

    char* p = (char*)d_ws;
    auto alloc = [&](size_t b) -> char* {
        char* r = p;
        p += (b + 255) & ~(size_t)255;
        return r;
    };
    float* dis = (float*)alloc(N_NODES * 4);
    float* inv = (float*)alloc(N_NODES * 4);
    float* t = (float*)alloc(N_NODES * 4);
    float* qe = (float*)alloc(129 * 4);
    float* a = (float*)alloc(N_NODES * 4);
    float* n2 = (float*)alloc(N_NODES * 4);
    float* u1 = (float*)alloc(N_NODES * 4);
    float* u2 = (float*)alloc(N_NODES * 4);
    float* r0v = (float*)alloc(128 * 4);
    float* r1v = (float*)alloc(128 * 4);
    float* g2v = (float*)alloc(128 * 4);
    int* flag = (int*)alloc(4);
    int* cnt = (int*)alloc(N_NODES * 4);
    int* cursor = (int*)alloc(N_NODES * 4);
    int* rowptr = (int*)alloc((N_NODES + 1) * 4);
    int* partial = (int*)alloc(64 * 4);
    int* col = (int*)alloc(N_EDGES * 4);
    unsigned short* Wb = (unsigned short*)alloc((size_t)11 * 16384 * 2);
    unsigned short* featsh = (unsigned short*)alloc((size_t)N_NODES * 128 * 2);
    unsigned short* z0h = (unsigned short*)alloc((size_t)N_NODES * 128 * 2);
    unsigned short* B1h = (unsigned short*)alloc((size_t)N_NODES * 384 * 2);
    unsigned short* B2h = (unsigned short*)alloc((size_t)N_NODES * 384 * 2);
    unsigned char* xq8 = (unsigned char*)alloc((size_t)N_NODES * 128);
    float* xf = (float*)alloc((size_t)N_NODES * 128 * 4);

    const int EB = (N_EDGES + 255) / 256;
    const int NB = (N_NODES + 255) / 256;
    const int NP = (N_NODES + 1023) / 1024;
    const int GB = (N_NODES + 127) / 128;

    hipMemsetAsync(cnt, 0, N_NODES * 4, stream);
    hipMemsetAsync(cursor, 0, N_NODES * 4, stream);
    hipMemsetAsync(t, 0, N_NODES * 4, stream);
    hipMemsetAsync(out + N_NODES, 0, 4, stream);

    // preprocessing
    k_count<<<EB, 256, 0, stream>>>(ei, cnt);
    k_invdis<<<NB, 256, 0, stream>>>(cnt, dis, inv);
    k_scan_partial<<<NP, 256, 0, stream>>>(cnt, partial);
    k_scan_mid<<<1, 64, 0, stream>>>(partial, rowptr);
    k_scan_final<<<NP, 256, 0, stream>>>(cnt, partial, rowptr);
    k_fill<<<EB, 256, 0, stream>>>(ei, rowptr, cursor, col);
    k_t<<<EB, 256, 0, stream>>>(ei, qp, dis, inv, t);
    k_flag<<<1, 256, 0, stream>>>(bq0, bq1, flag);
    k_cast<<<(N_NODES * 128 / 8 + 255) / 256, 256, 0, stream>>>(feats, featsh,
                                                                N_NODES * 128 / 8);
    WPack wp{{w_lf, wx0, wf0, wq1, wx1, wf1, wq2, wx2, wf2, m1w1, m1w2}};
    k_castw<<<dim3(8, 11), 256, 0, stream>>>(wp, Wb);

    // rank-1 path precompute (gated on flag==1)
    k_r0<<<1, 128, 0, stream>>>(flag, wq0, r0v);
    k_spmv<<<NB, 256, 0, stream>>>(flag, rowptr, col, dis, inv, t, u1);
    k_spmv<<<NB, 256, 0, stream>>>(flag, rowptr, col, dis, inv, u1, u2);
    k_matvec<1><<<128, 64, 0, stream>>>(flag, wq1, r0v, r1v);
    k_matvec<0><<<128, 64, 0, stream>>>(flag, wq2, r1v, g2v);

    // z0 = feats@w_lf.T + b_lf + b_lq (+ w_lq at row q)
    k_gemm<0, 0, 1, 0, 0><<<GB, 256, 0, stream>>>(featsh, 128, Wb + 0 * 16384, b_lf, b_lq,
                                                  nullptr, 0, nullptr, 0,
                                                  nullptr, nullptr, nullptr, 0,
                                                  z0h, 128, nullptr, 0, N_NODES);
    k_addwlq<<<1, 128, 0, stream>>>(qp, w_lq, z0h);

    // layer 0
    k_hq0<<<(N_NODES * 128) / 256, 256, 0, stream>>>(flag, t, wq0, bq0, B1h);
    k_agg<2><<<N_NODES / 4, 256, 0, stream>>>(nullptr, 0, rowptr, col, dis, inv,
                                              featsh, 128, z0h, 128, nullptr, 0,
                                              B2h, 128, 256, 0);
    k_gemm<1, 0, 0, 0, 0><<<GB, 256, 0, stream>>>(B2h + 128, 384, Wb + 1 * 16384, bx0, nullptr,
                                                  nullptr, 0, nullptr, 0,
                                                  nullptr, nullptr, nullptr, 0,
                                                  B1h + 128, 384, nullptr, 0, N_NODES);
    k_gemm<1, 2, 0, 0, 0><<<GB, 256, 0, stream>>>(B2h + 256, 384, Wb + 2 * 16384, bf0, nullptr,
                                                  B1h + 0, 384, B1h + 128, 384,
                                                  nullptr, nullptr, flag, 0,
                                                  B1h + 256, 384, nullptr, 0, N_NODES);
    k_gemm<1, 1, 0, 0, 1><<<GB, 256, 0, stream>>>(B2h + 256, 384, Wb + 2 * 16384, bf0, nullptr,
                                                  B1h + 128, 384, nullptr, 0,
                                                  t, r0v, flag, 1,
                                                  B1h + 256, 384, nullptr, 0, N_NODES);

    // layer 1
    k_agg<3><<<N_NODES / 4, 256, 0, stream>>>(flag, 0, rowptr, col, dis, inv,
                                              B1h, 384, B1h + 128, 384, B1h + 256, 384,
                                              B2h, 0, 128, 256);
    k_agg<2><<<N_NODES / 4, 256, 0, stream>>>(flag, 1, rowptr, col, dis, inv,
                                              B1h + 128, 384, B1h + 256, 384, nullptr, 0,
                                              B2h, 128, 256, 0);
    k_gemm<1, 0, 0, 0, 0><<<GB, 256, 0, stream>>>(B2h + 0, 384, Wb + 3 * 16384, bq1, nullptr,
                                                  nullptr, 0, nullptr, 0,
                                                  nullptr, nullptr, flag, 0,
                                                  B1h + 0, 384, nullptr, 0, N_NODES);
    k_gemm<1, 0, 0, 0, 0><<<GB, 256, 0, stream>>>(B2h + 128, 384, Wb + 4 * 16384, bx1, nullptr,
                                                  nullptr, 0, nullptr, 0,
                                                  nullptr, nullptr, nullptr, 0,
                                                  B1h + 128, 384, nullptr, 0, N_NODES);
    k_gemm<1, 2, 0, 0, 0><<<GB, 256, 0, stream>>>(B2h + 256, 384, Wb + 5 * 16384, bf1, nullptr,
                                                  B1h + 0, 384, B1h + 128, 384,
                                                  nullptr, nullptr, flag, 0,
                                                  B1h + 256, 384, nullptr, 0, N_NODES);
    k_gemm<1, 1, 0, 0, 1><<<GB, 256, 0, stream>>>(B2h + 256, 384, Wb + 5 * 16384, bf1, nullptr,
                                                  B1h + 128, 384, nullptr, 0,
                                                  u1, r1v, flag, 1,
                                                  B1h + 256, 384, nullptr, 0, N_NODES);

    // layer 2 (no relu)
    k_agg<3><<<N_NODES / 4, 256, 0, stream>>>(flag, 0, rowptr, col, dis, inv,
                                              B1h, 384, B1h + 128, 384, B1h + 256, 384,
                                              B2h, 0, 128, 256);
    k_agg<2><<<N_NODES / 4, 256, 0, stream>>>(flag, 1, rowptr, col, dis, inv,
                                              B1h + 128, 384, B1h + 256, 384, nullptr, 0,
                                              B2h, 128, 256, 0);
    k_gemm<0, 0, 0, 0, 0><<<GB, 256, 0, stream>>>(B2h + 0, 384, Wb + 6 * 16384, bq2, nullptr,
                                                  nullptr, 0, nullptr, 0,
                                                  nullptr, nullptr, flag, 0,
                                                  B1h + 0, 384, nullptr, 0, N_NODES);
    k_gemm<0, 0, 0, 0, 0><<<GB, 256, 0, stream>>>(B2h + 128, 384, Wb + 7 * 16384, bx2, nullptr,
                                                  nullptr, 0, nullptr, 0,
                                                  nullptr, nullptr, nullptr, 0,
                                                  B1h + 128, 384, nullptr, 0, N_NODES);
    k_gemm<0, 2, 0, 0, 0><<<GB, 256, 0, stream>>>(B2h + 256, 384, Wb + 8 * 16384, bf2, nullptr,
                                                  B1h + 0, 384, B1h + 128, 384,
                                                  nullptr, nullptr, flag, 0,
                                                  B1h + 256, 384, nullptr, 0, N_NODES);
    k_gemm<0, 1, 1, 0, 1><<<GB, 256, 0, stream>>>(B2h + 256, 384, Wb + 8 * 16384, bf2, bq2,
                                                  B1h + 128, 384, nullptr, 0,
                                                  u2, g2v, flag, 1,
                                                  B1h + 256, 384, nullptr, 0, N_NODES);

    // mlp1
    k_gemm<1, 0, 0, 0, 0><<<GB, 256, 0, stream>>>(B1h + 256, 384, Wb + 9 * 16384, m1b1, nullptr,
                                                  nullptr, 0, nullptr, 0,
                                                  nullptr, nullptr, nullptr, 0,
                                                  B2h + 0, 384, nullptr, 0, N_NODES);
    k_gemm<0, 0, 0, 1, 0><<<GB, 256, 0, stream>>>(B2h + 0, 384, Wb + 10 * 16384, m1b2, nullptr,
                                                  nullptr, 0, nullptr, 0,
                                                  nullptr, nullptr, nullptr, 0,
                                                  nullptr, 0, xf, 128, N_NODES);

    // decode
    k_cast8<<<(N_NODES * 8 + 255) / 256, 256, 0, stream>>>(xf, xq8);
    k_qemb<<<1, 128, 0, stream>>>(qp, xf, qe);
    k_node<<<N_NODES / 4, 256, 0, stream>>>(xf, qe, m2w1, m2b1, m2w2, m2b2, out, a, n2);
    k_loss<<<2048, 256, 0, stream>>>(ei, nei, xq8, a, n2, qe, out + N_NODES);
}